// Round 9
// baseline (258.730 us; speedup 1.0000x reference)
//
#include <hip/hip_runtime.h>
#include <hip/hip_bf16.h>

// GCN forward, algebraically collapsed (no nonlinearity between convs, mean pool):
//   g = (1/n)*((A^T u)^T X)@W1@W2 + (1/n)*(sum u)*(b1@W2) + b2,  A = D^-1/2(Adj+I)D^-1/2
// Round 9: ALL phases fused into ONE kernel (256 blocks x 1024 thr, 1 block/CU,
// co-resident) with device-scope counter barriers (validated rounds 6-8; the
// round-5 disaster was cg::grid.sync, not device barriers). Replaces 5 graph
// gaps + kernel ramp cycles with ~8 light barriers.

#define D_IN 128
#define D_HID 256
#define D_DENSE 128
#define R0 10240          // range-0 bins (40 KB LDS)
#define NSL 128           // edge slices == replicas per range
#define FOLD_B 192        // fold blocks
#define FOLD_C 105        // nodes per fold block (192*105 = 20160 >= N)
#define NTILE 157         // ceil(20000/128) tail tiles

__device__ __forceinline__ void g_arrive(unsigned* ctr) {
    __syncthreads();
    if (threadIdx.x == 0)
        __hip_atomic_fetch_add(ctr, 1u, __ATOMIC_RELEASE, __HIP_MEMORY_SCOPE_AGENT);
}
__device__ __forceinline__ void g_wait(unsigned* ctr, unsigned target) {
    if (threadIdx.x == 0) {
        while (__hip_atomic_load(ctr, __ATOMIC_ACQUIRE, __HIP_MEMORY_SCOPE_AGENT) < target)
            __builtin_amdgcn_s_sleep(2);
    }
    __syncthreads();
}

__global__ __launch_bounds__(1024) void k_all(
    const float* __restrict__ x, const int* __restrict__ row,
    const int* __restrict__ col, const float* __restrict__ w,
    const float* __restrict__ W1, const float* __restrict__ b1,
    const float* __restrict__ W2, const float* __restrict__ b2,
    const float* __restrict__ Wd1, const float* __restrict__ bd1,
    const float* __restrict__ Wd2, const float* __restrict__ bd2,
    float* __restrict__ part, float* __restrict__ dinv, float* __restrict__ u,
    float* __restrict__ s_part, float* __restrict__ S_u_part,
    float* __restrict__ S_u_g, float* __restrict__ M, float* __restrict__ c2,
    float* __restrict__ g_part, float* __restrict__ z_part,
    unsigned* __restrict__ ctr, float* __restrict__ out,
    int N, int E, float inv_n) {
    __shared__ float lds[R0];                     // 40 KB, reused per phase
    const int b = blockIdx.x, tid = threadIdx.x;

    // ---- edge scatter into this block's (slice, range) LDS histogram ------
    auto scatter = [&](const int* tgt, const int* src, int mode) {
        const int range = b & 1, slice = b >> 1;
        const int base = range ? R0 : 0;
        const int lim  = range ? (N - R0) : R0;
        const int per = (E + NSL - 1) / NSL;      // 5000
        const int e0 = slice * per, e1 = min(e0 + per, E);
        float* outp = part + (range ? (size_t)NSL * R0 + (size_t)slice * lim
                                    : (size_t)slice * lim);
        for (int i = tid; i < lim; i += 1024) lds[i] = 0.f;
        __syncthreads();
        for (int e = e0 + tid; e < e1; e += 1024) {
            int t = tgt[e] - base;
            if ((unsigned)t < (unsigned)lim) {
                float v = w[e];
                if (mode != 0) {
                    int c = src[e];
                    float dc = dinv[c];
                    v *= (mode == 2) ? dc * u[c] : dc;
                }
                atomicAdd(&lds[t], v);            // LDS atomic
            }
        }
        __syncthreads();
        for (int i = tid; i < lim; i += 1024) outp[i] = lds[i];
    };

    // ---- fold 128 replicas + node math (blocks 0..FOLD_B-1) ---------------
    auto fold = [&](int mode) {
        const int j = tid & 127, rg = tid >> 7;
        const int i = b * FOLD_C + j;
        const bool act = (j < FOLD_C) && (i < N);
        float sv = 0.f;
        if (act) {
            size_t st; const float* pp;
            if (i < R0) { st = R0;               pp = part + i; }
            else        { st = (size_t)(N - R0); pp = part + (size_t)NSL * R0 + (i - R0); }
            pp += (size_t)rg * 16 * st;
            #pragma unroll
            for (int r = 0; r < 16; ++r) sv += pp[(size_t)r * st];
        }
        lds[rg * 128 + j] = sv;
        __syncthreads();
        float ui = 0.f;
        if (rg == 0) {
            float tot = 0.f;
            #pragma unroll
            for (int q = 0; q < 8; ++q) tot += lds[q * 128 + j];
            if (act) {
                if (mode == 0) dinv[i] = rsqrtf(tot + 1.0f);      // +1 self-loop
                else { float d = dinv[i]; ui = d * (tot + d); u[i] = ui; }
            }
        }
        if (mode == 1) {                          // per-block S_u partial
            float v = ui;                         // nonzero only in waves 0-1
            #pragma unroll
            for (int off = 32; off > 0; off >>= 1) v += __shfl_down(v, off, 64);
            if (tid < 128 && (tid & 63) == 0) lds[1030 + (tid >> 6)] = v;
            __syncthreads();
            if (tid == 0) S_u_part[b] = lds[1030] + lds[1031];
        }
    };

    // ---- M = W1@W2, c2 = b1@W2 (blocks FOLD_B..255 during F0) -------------
    auto precompute = [&]() {
        int q = b - FOLD_B;                       // 0..63: 4 cols each
        lds[tid] = W2[(tid >> 2) * 256 + q * 4 + (tid & 3)];
        __syncthreads();
        int wvi = tid >> 6, lane = tid & 63;
        for (int kr = 0; kr < 8; ++kr) {
            int k = wvi * 8 + kr;                 // 16 waves x 8 = 128 rows
            float a0 = 0, a1 = 0, a2 = 0, a3 = 0;
            #pragma unroll
            for (int it = 0; it < 4; ++it) {
                int j = it * 64 + lane;
                float a = W1[k * 256 + j];
                a0 += a * lds[j*4+0]; a1 += a * lds[j*4+1];
                a2 += a * lds[j*4+2]; a3 += a * lds[j*4+3];
            }
            #pragma unroll
            for (int off = 32; off > 0; off >>= 1) {
                a0 += __shfl_down(a0, off, 64); a1 += __shfl_down(a1, off, 64);
                a2 += __shfl_down(a2, off, 64); a3 += __shfl_down(a3, off, 64);
            }
            if (lane == 0) {
                M[k * 256 + q*4 + 0] = a0; M[k * 256 + q*4 + 1] = a1;
                M[k * 256 + q*4 + 2] = a2; M[k * 256 + q*4 + 3] = a3;
            }
        }
        if (wvi == 0) {
            float a0 = 0, a1 = 0, a2 = 0, a3 = 0;
            #pragma unroll
            for (int it = 0; it < 4; ++it) {
                int j = it * 64 + lane;
                float a = b1[j];
                a0 += a * lds[j*4+0]; a1 += a * lds[j*4+1];
                a2 += a * lds[j*4+2]; a3 += a * lds[j*4+3];
            }
            #pragma unroll
            for (int off = 32; off > 0; off >>= 1) {
                a0 += __shfl_down(a0, off, 64); a1 += __shfl_down(a1, off, 64);
                a2 += __shfl_down(a2, off, 64); a3 += __shfl_down(a3, off, 64);
            }
            if (lane == 0) {
                c2[q*4+0] = a0; c2[q*4+1] = a1;
                c2[q*4+2] = a2; c2[q*4+3] = a3;
            }
        }
    };

    // ---- tail A: fold wv for tile b, contract against x -> s_part ---------
    auto tailA = [&]() {
        const int k = tid & 127, rg = tid >> 7;
        const int i0 = b * 128, i = i0 + k;
        const bool act = i < N;
        float sv = 0.f;
        if (act) {
            size_t st; const float* pp;
            if (i < R0) { st = R0;               pp = part + i; }
            else        { st = (size_t)(N - R0); pp = part + (size_t)NSL * R0 + (i - R0); }
            pp += (size_t)rg * 16 * st;
            #pragma unroll
            for (int r = 0; r < 16; ++r) sv += pp[(size_t)r * st];
        }
        lds[tid] = sv;
        __syncthreads();
        if (rg == 0) {
            float qq = 0.f;
            #pragma unroll
            for (int t2 = 0; t2 < 8; ++t2) qq += lds[t2 * 128 + k];
            float d = act ? dinv[i] : 0.f;
            lds[1024 + k] = act ? d * (qq + d * u[i]) : 0.f;   // wv tile
        }
        __syncthreads();
        float acc = 0.f;
        #pragma unroll
        for (int jj = 0; jj < 16; ++jj) {
            int m = rg + 8 * jj;
            int i2 = i0 + m;
            float xv = x[(size_t)(i2 < N ? i2 : i0) * D_IN + k];
            acc += lds[1024 + m] * xv;
        }
        __syncthreads();
        lds[tid] = acc;
        __syncthreads();
        if (rg == 0) {
            float t2s = 0.f;
            #pragma unroll
            for (int t2 = 0; t2 < 8; ++t2) t2s += lds[t2 * 128 + k];
            s_part[b * 128 + k] = t2s;
        }
    };

    // ---- tail B: fold s + S_u; g_part rows [8b,8b+8) ----------------------
    auto tailB = [&]() {
        const int k = tid & 127, rg = tid >> 7;
        float a2 = 0.f;
        for (int q = rg; q < NTILE; q += 8) a2 += s_part[q * 128 + k];
        lds[tid] = a2;
        float v = 0.f;
        if (b == 0) {
            v = (tid < FOLD_B) ? S_u_part[tid] : 0.f;
            #pragma unroll
            for (int off = 32; off > 0; off >>= 1) v += __shfl_down(v, off, 64);
        }
        __syncthreads();
        if (rg == 0) {
            float t2 = 0.f;
            #pragma unroll
            for (int q = 0; q < 8; ++q) t2 += lds[q * 128 + k];
            lds[1024 + k] = t2;                   // s[k]
        }
        if (b == 0 && (tid & 63) == 0) lds[1160 + (tid >> 6)] = v;
        __syncthreads();
        if (b == 0 && tid == 0) {
            float t2 = 0.f;
            #pragma unroll
            for (int q = 0; q < 16; ++q) t2 += lds[1160 + q];
            S_u_g[0] = t2;
        }
        if (tid < 256) {
            float gp = 0.f;
            #pragma unroll
            for (int kk = 0; kk < 8; ++kk)
                gp += lds[1024 + b * 8 + kk] * M[(b * 8 + kk) * 256 + tid];
            g_part[b * 256 + tid] = gp;
        }
    };

    // ---- tail C: fold g slice; z_part ------------------------------------
    auto tailC = [&]() {
        if (tid < 16) {
            int kk = b * 16 + tid;
            float gval = 0.f;
            #pragma unroll
            for (int p2 = 0; p2 < 16; ++p2) gval += g_part[p2 * 256 + kk];
            lds[tid] = (gval + S_u_g[0] * c2[kk]) * inv_n + b2[kk];
        }
        __syncthreads();
        if (tid < 128) {
            float z = 0.f;
            #pragma unroll
            for (int kk = 0; kk < 16; ++kk)
                z += lds[kk] * Wd1[(b * 16 + kk) * D_DENSE + tid];
            z_part[b * 128 + tid] = z;
        }
    };

    // ---- tail D: fold z, relu, logits, softmax ----------------------------
    auto tailD = [&]() {
        float p0 = 0.f, p1 = 0.f;
        if (tid < 128) {
            float zr = bd1[tid];
            #pragma unroll
            for (int p2 = 0; p2 < 16; ++p2) zr += z_part[p2 * 128 + tid];
            float zt = fmaxf(zr, 0.f);
            p0 = zt * Wd2[tid * 2 + 0];
            p1 = zt * Wd2[tid * 2 + 1];
        }
        #pragma unroll
        for (int off = 32; off > 0; off >>= 1) {
            p0 += __shfl_down(p0, off, 64);
            p1 += __shfl_down(p1, off, 64);
        }
        if ((tid & 63) == 0) { lds[32 + (tid >> 6)] = p0; lds[64 + (tid >> 6)] = p1; }
        __syncthreads();
        if (tid == 0) {
            float l0 = bd2[0], l1 = bd2[1];
            #pragma unroll
            for (int q = 0; q < 16; ++q) { l0 += lds[32 + q]; l1 += lds[64 + q]; }
            float m = fmaxf(l0, l1);
            float e0 = expf(l0 - m), e1 = expf(l1 - m);
            float inv = 1.0f / (e0 + e1);
            out[0] = e0 * inv;
            out[1] = e1 * inv;
        }
    };

    // ---------------- phase schedule ----------------------------------------
    scatter(col, row, 0);                         // deg by col
    g_arrive(ctr); g_wait(ctr, 256);
    if (b < FOLD_B) fold(0); else precompute();   // dinv | M,c2
    g_arrive(ctr); g_wait(ctr, 512);
    scatter(row, col, 1);                         // gather dinv[c]
    g_arrive(ctr); g_wait(ctr, 768);
    if (b < FOLD_B) fold(1);                      // u, S_u partials
    g_arrive(ctr); g_wait(ctr, 1024);
    scatter(row, col, 2);                         // gather dinv[c]*u[c]
    g_arrive(ctr); g_wait(ctr, 1280);
    if (b < NTILE) tailA();                       // wv tile + x contraction
    g_arrive(ctr);
    if (b >= 16) return;
    g_wait(ctr, 1536);
    tailB();                                      // s, S_u, g_part
    g_arrive(ctr); g_wait(ctr, 1552);
    tailC();                                      // g fold, z_part
    g_arrive(ctr);
    if (b != 0) return;
    g_wait(ctr, 1568);
    tailD();                                      // logits, softmax
}

extern "C" void kernel_launch(void* const* d_in, const int* in_sizes, int n_in,
                              void* d_out, int out_size, void* d_ws, size_t ws_size,
                              hipStream_t stream) {
    const float* x   = (const float*)d_in[0];
    const int*   ei  = (const int*)  d_in[1];
    const float* w   = (const float*)d_in[2];
    const float* W1  = (const float*)d_in[3];
    const float* b1  = (const float*)d_in[4];
    const float* W2  = (const float*)d_in[5];
    const float* b2  = (const float*)d_in[6];
    const float* Wd1 = (const float*)d_in[7];
    const float* bd1 = (const float*)d_in[8];
    const float* Wd2 = (const float*)d_in[9];
    const float* bd2 = (const float*)d_in[10];
    float* out = (float*)d_out;

    const int N = in_sizes[0] / D_IN;      // 20000
    const int E = in_sizes[1] / 2;         // 640000
    const int* row = ei;
    const int* col = ei + E;

    // workspace layout. All buffers written before read; ctr zeroed by memset.
    unsigned* ctr = (unsigned*)d_ws;                       // 16 slots
    float* fws    = (float*)d_ws + 16;
    float* part   = fws;                                   // NSL*N = 2.56M
    float* dinv   = part + (size_t)NSL * N;                // N
    float* u      = dinv + N;                              // N
    float* s_part = u + N;                                 // NTILE*128
    float* S_u_p  = s_part + (size_t)NTILE * D_IN;         // FOLD_B
    float* S_u_g  = S_u_p + FOLD_B;                        // 1
    float* M      = S_u_g + 1;                             // 128*256
    float* c2     = M + D_IN * D_HID;                      // 256
    float* g_part = c2 + D_HID;                            // 16*256
    float* z_part = g_part + 16 * D_HID;                   // 16*128

    hipMemsetAsync(ctr, 0, 64, stream);                    // unpoison barrier ctr

    k_all<<<256, 1024, 0, stream>>>(x, row, col, w, W1, b1, W2, b2,
                                    Wd1, bd1, Wd2, bd2,
                                    part, dinv, u, s_part, S_u_p, S_u_g,
                                    M, c2, g_part, z_part, ctr, out,
                                    N, E, 1.0f / (float)N);
}

// Round 10
// 152.136 us; speedup vs baseline: 1.7007x; 1.7007x over previous
//
#include <hip/hip_runtime.h>
#include <hip/hip_bf16.h>

// GCN forward, algebraically collapsed (no nonlinearity between convs, mean pool):
//   g = (1/n)*((A^T u)^T X)@W1@W2 + (1/n)*(sum u)*(b1@W2) + b2,  A = D^-1/2(Adj+I)D^-1/2
// Round 10: NO intra-kernel grid barriers anywhere (measured rounds 5/9: any
// agent-scope release/acquire barrier costs ~25us on gfx950 — per-XCD L2
// writeback/invalidate walks; kernel boundaries cost ~2-3us). 7 plain
// dispatches; head is a single 1024-thread block using only __syncthreads.

#define D_IN 128
#define D_HID 256
#define D_DENSE 128
#define R0 10240          // range-0 bins (40 KB LDS); R1 = N-R0 = 9760
#define NSL 128           // edge slices == replicas per range
#define NTILE 157         // ceil(20000/128): fold/tail tiles of 128 nodes

// ---- edge scatter: block = (slice, range); LDS histogram of own range -----
// mode 0: bin[col[e]] += w[e]
// mode 1: bin[row[e]] += w[e]*dinv[col[e]]
// mode 2: bin[row[e]] += w[e]*dinv[col[e]]*u[col[e]]
__global__ __launch_bounds__(1024) void k_scatter(
    const int* __restrict__ tgt, const int* __restrict__ src,
    const float* __restrict__ w, const float* __restrict__ dinv,
    const float* __restrict__ u, float* __restrict__ part,
    int E, int N, int mode) {
    __shared__ float acc[R0];
    const int range = blockIdx.x & 1;
    const int slice = blockIdx.x >> 1;           // 0..NSL-1
    const int base  = range ? R0 : 0;
    const int lim   = range ? (N - R0) : R0;
    const int per = (E + NSL - 1) / NSL;         // 5000
    const int e0 = slice * per, e1 = min(e0 + per, E);
    float* outp = part + (range ? (size_t)NSL * R0 + (size_t)slice * lim
                                : (size_t)slice * lim);
    for (int i = threadIdx.x; i < lim; i += 1024) acc[i] = 0.f;
    __syncthreads();
    for (int e = e0 + threadIdx.x; e < e1; e += 1024) {
        int t = tgt[e] - base;
        if ((unsigned)t < (unsigned)lim) {
            float v = w[e];
            if (mode != 0) {
                int c = src[e];
                float dc = dinv[c];
                v *= (mode == 2) ? dc * u[c] : dc;
            }
            atomicAdd(&acc[t], v);               // LDS atomic
        }
    }
    __syncthreads();
    for (int i = threadIdx.x; i < lim; i += 1024) outp[i] = acc[i];
}

// ---- fold 128 replicas + node math; mode-0 spare blocks do M=W1@W2 --------
__global__ __launch_bounds__(1024) void k_fold(
    const float* __restrict__ part, float* __restrict__ dinv,
    float* __restrict__ u, float* __restrict__ S_u_part,
    const float* __restrict__ W1, const float* __restrict__ b1,
    const float* __restrict__ W2, float* __restrict__ M, float* __restrict__ c2,
    int N, int mode) {
    __shared__ float lds[1056];
    const int b = blockIdx.x, tid = threadIdx.x;

    if (b >= NTILE) {                            // ---- M / c2 precompute ----
        int q = b - NTILE;                       // 0..63: 4 cols of M each
        lds[tid] = W2[(tid >> 2) * 256 + q * 4 + (tid & 3)];
        __syncthreads();
        int wvi = tid >> 6, lane = tid & 63;
        for (int kr = 0; kr < 8; ++kr) {
            int k = wvi * 8 + kr;                // 16 waves x 8 = 128 rows
            float a0 = 0, a1 = 0, a2 = 0, a3 = 0;
            #pragma unroll
            for (int it = 0; it < 4; ++it) {
                int j = it * 64 + lane;
                float a = W1[k * 256 + j];
                a0 += a * lds[j*4+0]; a1 += a * lds[j*4+1];
                a2 += a * lds[j*4+2]; a3 += a * lds[j*4+3];
            }
            #pragma unroll
            for (int off = 32; off > 0; off >>= 1) {
                a0 += __shfl_down(a0, off, 64); a1 += __shfl_down(a1, off, 64);
                a2 += __shfl_down(a2, off, 64); a3 += __shfl_down(a3, off, 64);
            }
            if (lane == 0) {
                M[k * 256 + q*4 + 0] = a0; M[k * 256 + q*4 + 1] = a1;
                M[k * 256 + q*4 + 2] = a2; M[k * 256 + q*4 + 3] = a3;
            }
        }
        if (wvi == 0) {                          // c2 = b1 @ W2 slab
            float a0 = 0, a1 = 0, a2 = 0, a3 = 0;
            #pragma unroll
            for (int it = 0; it < 4; ++it) {
                int j = it * 64 + lane;
                float a = b1[j];
                a0 += a * lds[j*4+0]; a1 += a * lds[j*4+1];
                a2 += a * lds[j*4+2]; a3 += a * lds[j*4+3];
            }
            #pragma unroll
            for (int off = 32; off > 0; off >>= 1) {
                a0 += __shfl_down(a0, off, 64); a1 += __shfl_down(a1, off, 64);
                a2 += __shfl_down(a2, off, 64); a3 += __shfl_down(a3, off, 64);
            }
            if (lane == 0) {
                c2[q*4+0] = a0; c2[q*4+1] = a1;
                c2[q*4+2] = a2; c2[q*4+3] = a3;
            }
        }
        return;
    }

    // ---- replica fold: 128 nodes/block, 8 rgroups x 16 replicas -----------
    const int j = tid & 127, rg = tid >> 7;
    const int i = b * 128 + j;                   // tile 80 starts at R0 exactly
    const bool act = i < N;
    float sv = 0.f;
    if (act) {
        size_t st; const float* pp;
        if (i < R0) { st = R0;               pp = part + i; }
        else        { st = (size_t)(N - R0); pp = part + (size_t)NSL * R0 + (i - R0); }
        pp += (size_t)rg * 16 * st;
        #pragma unroll
        for (int r = 0; r < 16; ++r) sv += pp[(size_t)r * st];
    }
    lds[rg * 128 + j] = sv;
    __syncthreads();
    float ui = 0.f;
    if (rg == 0) {
        float tot = 0.f;
        #pragma unroll
        for (int q = 0; q < 8; ++q) tot += lds[q * 128 + j];
        if (act) {
            if (mode == 0) dinv[i] = rsqrtf(tot + 1.0f);          // +1 self-loop
            else { float d = dinv[i]; ui = d * (tot + d); u[i] = ui; }
        }
    }
    if (mode == 1) {                             // per-block S_u partial
        float v = ui;                            // nonzero only in waves 0-1
        #pragma unroll
        for (int off = 32; off > 0; off >>= 1) v += __shfl_down(v, off, 64);
        if (tid < 128 && (tid & 63) == 0) lds[1028 + (tid >> 6)] = v;
        __syncthreads();
        if (tid == 0) S_u_part[b] = lds[1028] + lds[1029];
    }
}

// ---- tailA: fold wv for tile b (128 nodes), contract against x ------------
__global__ __launch_bounds__(1024) void k_tailA(
    const float* __restrict__ x, const float* __restrict__ part,
    const float* __restrict__ dinv, const float* __restrict__ u,
    float* __restrict__ s_part, int N) {
    __shared__ float sh[1024];
    __shared__ float wvl[128];
    const int b = blockIdx.x, tid = threadIdx.x;
    const int k = tid & 127, rg = tid >> 7;
    const int i0 = b * 128, i = i0 + k;
    const bool act = i < N;
    float sv = 0.f;
    if (act) {
        size_t st; const float* pp;
        if (i < R0) { st = R0;               pp = part + i; }
        else        { st = (size_t)(N - R0); pp = part + (size_t)NSL * R0 + (i - R0); }
        pp += (size_t)rg * 16 * st;
        #pragma unroll
        for (int r = 0; r < 16; ++r) sv += pp[(size_t)r * st];
    }
    sh[tid] = sv;
    __syncthreads();
    if (rg == 0) {
        float q = 0.f;
        #pragma unroll
        for (int t2 = 0; t2 < 8; ++t2) q += sh[t2 * 128 + k];
        float d = act ? dinv[i] : 0.f;
        wvl[k] = act ? d * (q + d * u[i]) : 0.f;   // wv = dinv*(q + dinv*u)
    }
    __syncthreads();
    float acc = 0.f;
    #pragma unroll
    for (int jj = 0; jj < 16; ++jj) {
        int m = rg + 8 * jj;
        int i2 = i0 + m;
        float xv = x[(size_t)(i2 < N ? i2 : i0) * D_IN + k];
        acc += wvl[m] * xv;
    }
    __syncthreads();
    sh[tid] = acc;
    __syncthreads();
    if (rg == 0) {
        float t2s = 0.f;
        #pragma unroll
        for (int t2 = 0; t2 < 8; ++t2) t2s += sh[t2 * 128 + k];
        s_part[b * 128 + k] = t2s;
    }
}

// ---- head: ONE block x 1024 threads, __syncthreads only --------------------
__global__ __launch_bounds__(1024) void k_head(
    const float* __restrict__ s_part, const float* __restrict__ S_u_part,
    const float* __restrict__ M, const float* __restrict__ c2,
    const float* __restrict__ b2, const float* __restrict__ Wd1,
    const float* __restrict__ bd1, const float* __restrict__ Wd2,
    const float* __restrict__ bd2, float* __restrict__ out, float inv_n) {
    __shared__ float sh[1024];
    __shared__ float ss[128];
    __shared__ float gg[256];
    __shared__ float zz[128];
    __shared__ float red[40];
    const int tid = threadIdx.x;
    const int k = tid & 127, rg = tid >> 7;

    // s fold (157 tiles) + S_u fold (157 partials)
    float a = 0.f;
    for (int q = rg; q < NTILE; q += 8) a += s_part[q * 128 + k];
    sh[tid] = a;
    float v = (tid < NTILE) ? S_u_part[tid] : 0.f;
    #pragma unroll
    for (int off = 32; off > 0; off >>= 1) v += __shfl_down(v, off, 64);
    __syncthreads();
    if (rg == 0) {
        float t2 = 0.f;
        #pragma unroll
        for (int q = 0; q < 8; ++q) t2 += sh[q * 128 + k];
        ss[k] = t2;
    }
    if ((tid & 63) == 0) red[tid >> 6] = v;
    __syncthreads();
    if (tid == 0) {
        float t2 = 0.f;
        #pragma unroll
        for (int q = 0; q < 16; ++q) t2 += red[q];
        red[16] = t2;
    }
    __syncthreads();
    const float S_u = red[16];

    // g = (s@M + S_u*c2)/n + b2 : t = tid&255, 4 k-groups of 32
    {
        int t = tid & 255, kg = tid >> 8;
        float acc = 0.f;
        #pragma unroll
        for (int kk = 0; kk < 32; ++kk) {
            int k2 = kg * 32 + kk;
            acc += ss[k2] * M[k2 * 256 + t];
        }
        sh[tid] = acc;
        __syncthreads();
        if (kg == 0)
            gg[t] = (sh[t] + sh[256 + t] + sh[512 + t] + sh[768 + t]
                     + S_u * c2[t]) * inv_n + b2[t];
    }
    __syncthreads();

    // z = relu(g@Wd1 + bd1) : t = tid&127, 8 k-groups of 32
    {
        float acc = 0.f;
        #pragma unroll
        for (int kk = 0; kk < 32; ++kk) {
            int k2 = rg * 32 + kk;
            acc += gg[k2] * Wd1[k2 * D_DENSE + k];
        }
        sh[tid] = acc;
        __syncthreads();
        if (rg == 0) {
            float z = 0.f;
            #pragma unroll
            for (int q = 0; q < 8; ++q) z += sh[q * 128 + k];
            zz[k] = fmaxf(z + bd1[k], 0.f);
        }
    }
    __syncthreads();

    // logits + softmax
    float p0 = 0.f, p1 = 0.f;
    if (tid < 128) {
        float zt = zz[tid];
        p0 = zt * Wd2[tid * 2 + 0];
        p1 = zt * Wd2[tid * 2 + 1];
    }
    #pragma unroll
    for (int off = 32; off > 0; off >>= 1) {
        p0 += __shfl_down(p0, off, 64);
        p1 += __shfl_down(p1, off, 64);
    }
    if ((tid & 63) == 0) { red[tid >> 6] = p0; red[20 + (tid >> 6)] = p1; }
    __syncthreads();
    if (tid == 0) {
        float l0 = red[0] + red[1] + bd2[0];     // only waves 0-1 nonzero
        float l1 = red[20] + red[21] + bd2[1];
        float m = fmaxf(l0, l1);
        float e0 = expf(l0 - m), e1 = expf(l1 - m);
        float inv = 1.0f / (e0 + e1);
        out[0] = e0 * inv;
        out[1] = e1 * inv;
    }
}

extern "C" void kernel_launch(void* const* d_in, const int* in_sizes, int n_in,
                              void* d_out, int out_size, void* d_ws, size_t ws_size,
                              hipStream_t stream) {
    const float* x   = (const float*)d_in[0];
    const int*   ei  = (const int*)  d_in[1];
    const float* w   = (const float*)d_in[2];
    const float* W1  = (const float*)d_in[3];
    const float* b1  = (const float*)d_in[4];
    const float* W2  = (const float*)d_in[5];
    const float* b2  = (const float*)d_in[6];
    const float* Wd1 = (const float*)d_in[7];
    const float* bd1 = (const float*)d_in[8];
    const float* Wd2 = (const float*)d_in[9];
    const float* bd2 = (const float*)d_in[10];
    float* out = (float*)d_out;

    const int N = in_sizes[0] / D_IN;      // 20000
    const int E = in_sizes[1] / 2;         // 640000
    const int* row = ei;
    const int* col = ei + E;

    // workspace (floats); every buffer is written before it is read — no memset
    float* fws    = (float*)d_ws;
    float* part   = fws;                                   // NSL*N
    float* dinv   = part + (size_t)NSL * N;                // N
    float* u      = dinv + N;                              // N
    float* s_part = u + N;                                 // NTILE*128
    float* S_u_p  = s_part + (size_t)NTILE * D_IN;         // NTILE
    float* M      = S_u_p + NTILE;                         // 128*256
    float* c2     = M + D_IN * D_HID;                      // 256

    // pass 1: deg by col -> dinv; spare fold blocks compute M=W1@W2, c2=b1@W2
    k_scatter<<<2 * NSL, 1024, 0, stream>>>(col, row, w, dinv, u, part, E, N, 0);
    k_fold<<<NTILE + 64, 1024, 0, stream>>>(part, dinv, u, S_u_p, W1, b1, W2, M, c2, N, 0);
    // pass 2: by row, gather dinv[col] -> u, S_u partials
    k_scatter<<<2 * NSL, 1024, 0, stream>>>(row, col, w, dinv, u, part, E, N, 1);
    k_fold<<<NTILE, 1024, 0, stream>>>(part, dinv, u, S_u_p, W1, b1, W2, M, c2, N, 1);
    // pass 3: by row, gather dinv[col]*u[col]
    k_scatter<<<2 * NSL, 1024, 0, stream>>>(row, col, w, dinv, u, part, E, N, 2);
    // wv fold + feature contraction
    k_tailA<<<NTILE, 1024, 0, stream>>>(x, part, dinv, u, s_part, N);
    // dense head, single block (reads ~340 KB at 16 waves; no grid barrier)
    k_head<<<1, 1024, 0, stream>>>(s_part, S_u_p, M, c2, b2, Wd1, bd1, Wd2, bd2,
                                   out, 1.0f / (float)N);
}